// Round 12
// baseline (123.272 us; speedup 1.0000x reference)
//
#include <hip/hip_runtime.h>

#define BB 4096   // batch
#define TT 512    // time steps
#define DD 32     // input dim
#define NL 10     // layers
#define PH 8      // steps per phase
#define PHASES 66 // 528 steps
#define CPB 4     // chains per block (R10 config: 1024 blocks, 1 wave/SIMD)

static constexpr float L2E = 1.4426950408889634f;   // log2(e)

typedef float f4 __attribute__((ext_vector_type(4)));

__device__ __forceinline__ float fexp2(float x) { return __builtin_amdgcn_exp2f(x); }
__device__ __forceinline__ float frcp(float x)  { return __builtin_amdgcn_rcpf(x); }
__device__ __forceinline__ float fmed3(float x, float a, float b) {
    return __builtin_amdgcn_fmed3f(x, a, b);
}

// row_shr:1 within each 16-lane row; row-lane 0 gets 0 (bound_ctrl).
__device__ __forceinline__ float dpp_shr1(float x) {
    int r = __builtin_amdgcn_update_dpp(0, __float_as_int(x), 0x111, 0xF, 0xF, true);
    return __int_as_float(r);
}

// x + dpp_perm(x): pure-VALU lane reduction (no LDS, no lgkmcnt).
template<int CTRL>
__device__ __forceinline__ float dpp_add(float x) {
    return x + __int_as_float(__builtin_amdgcn_update_dpp(
        0, __float_as_int(x), CTRL, 0xF, 0xF, true));
}
#define DPP_XOR1 0xB1   // quad_perm [1,0,3,2]
#define DPP_XOR2 0x4E   // quad_perm [2,3,0,1]
#define DPP_ROR4 0x124  // row_ror:4 cross-quad gather (verified by R10 pass)

// ---------------------------------------------------------------------------
// R12 = R10 + 2-way in-lane ILP. Each wave: 4 rows x 16 lanes, one chain per
// row as in R10, but TWO pipeline register sets:
//   A-state is authoritative for rows 0,1; B-state for rows 2,3.
// All rows execute both A and B streams (wave64 issue is shared anyway);
// the per-row store selects the right one. The two streams are independent
// dependency chains -> B's instructions fill A's exp/rcp latency bubbles.
// Producer (DPP-reduce), LOADV, READR, G0 regs: shared, unchanged from R10.
// ---------------------------------------------------------------------------
__global__ __launch_bounds__(64) void k_fused(
    const float* __restrict__ x, const float* __restrict__ Wih0,
    const float* __restrict__ Whh0, const float* __restrict__ b0,
    const float* __restrict__ Wihr, const float* __restrict__ Whhr,
    const float* __restrict__ br, float* __restrict__ out)
{
    __shared__ float4 gbuf[2][CPB][PH + 1];   // [slot][chain][step], +1 pad

    const int lane = threadIdx.x & 63;
    const int blk  = blockIdx.x;

    // ---- producer-role constants ----
    const int pg = lane >> 3;               // step-in-phase this lane helps produce
    const int pc = lane & 7;                // float4 chunk of the 32-wide x row
    const f4 pw0 = *(const f4*)(Wih0 + 0 * DD + pc * 4);
    const f4 pw1 = *(const f4*)(Wih0 + 1 * DD + pc * 4);
    const f4 pw2 = *(const f4*)(Wih0 + 2 * DD + pc * 4);
    const f4 pw3 = *(const f4*)(Wih0 + 3 * DD + pc * 4);
    const float pb0 = b0[0], pb1 = b0[1], pb2 = b0[2], pb3 = b0[3];

    // ---- consumer-role constants ----
    const int cidx = lane >> 4;             // row = chain-in-block
    const int l = lane & 15;                // 0..9 live layers
    const int chain = blk * CPB + cidx;
    const float sk0 = -L2E, sk1 = -L2E, sk2 = -2.f * L2E, sk3 = -L2E;
    const bool isl0 = (l == 0), isl9 = (l == NL - 1);
    const bool rowA = (cidx < 2);           // which pipeline owns this row
    const int li = (l >= 1 && l <= 9) ? (l - 1) : 0;

    float wi0 = 0, wi1 = 0, wi2 = 0, wi3 = 0;
    float wh0, wh1, wh2, wh3;
    float bb0 = 0, bb1 = 0, bb2 = 0, bb3 = 0;
    if (isl0) {
        wh0 = sk0 * Whh0[0]; wh1 = sk1 * Whh0[1];
        wh2 = sk2 * Whh0[2]; wh3 = sk3 * Whh0[3];
    } else {
        const float* pi = Wihr + li * 4;
        const float* ph = Whhr + li * 4;
        const float* pb = br   + li * 4;
        wi0 = sk0 * pi[0]; wi1 = sk1 * pi[1]; wi2 = sk2 * pi[2]; wi3 = sk3 * pi[3];
        wh0 = sk0 * ph[0]; wh1 = sk1 * ph[1]; wh2 = sk2 * ph[2]; wh3 = sk3 * ph[3];
        bb0 = sk0 * pb[0]; bb1 = sk1 * pb[1]; bb2 = sk2 * pb[2]; bb3 = sk3 * pb[3];
    }

    float* outp = out + (size_t)chain * TT;
    const float c2 = 2.f * L2E;
    float hA = 0.f, csA = 0.f;              // pipeline A state (rows 0,1 real)
    float hB = 0.f, csB = 0.f;              // pipeline B state (rows 2,3 real)
    float o0 = 0.f, o1 = 0.f, o2 = 0.f, o3 = 0.f;   // per-row selected slots

    const float* xb = x + (size_t)blk * CPB * TT * DD;

    f4 VA0, VA1, VA2, VA3, VB0, VB1, VB2, VB3;

    auto LOADV = [&](f4& v0, f4& v1, f4& v2, f4& v3, int p) {
        int t = p * PH + pg; t = t < TT ? t : TT - 1;   // tail clamps (discarded)
        const float* base = xb + (size_t)t * DD + pc * 4;
        v0 = __builtin_nontemporal_load((const f4*)(base + 0 * TT * DD));
        v1 = __builtin_nontemporal_load((const f4*)(base + 1 * TT * DD));
        v2 = __builtin_nontemporal_load((const f4*)(base + 2 * TT * DD));
        v3 = __builtin_nontemporal_load((const f4*)(base + 3 * TT * DD));
    };

    auto PROD1 = [&](const f4 v, int ci, int slot) {    // ci, slot literal at call site
        float p0 = v.x * pw0.x + v.y * pw0.y + v.z * pw0.z + v.w * pw0.w;
        float p1 = v.x * pw1.x + v.y * pw1.y + v.z * pw1.z + v.w * pw1.w;
        float p2 = v.x * pw2.x + v.y * pw2.y + v.z * pw2.z + v.w * pw2.w;
        float p3 = v.x * pw3.x + v.y * pw3.y + v.z * pw3.z + v.w * pw3.w;
        p0 = dpp_add<DPP_XOR1>(p0); p1 = dpp_add<DPP_XOR1>(p1);
        p2 = dpp_add<DPP_XOR1>(p2); p3 = dpp_add<DPP_XOR1>(p3);
        p0 = dpp_add<DPP_XOR2>(p0); p1 = dpp_add<DPP_XOR2>(p1);
        p2 = dpp_add<DPP_XOR2>(p2); p3 = dpp_add<DPP_XOR2>(p3);
        p0 = dpp_add<DPP_ROR4>(p0); p1 = dpp_add<DPP_ROR4>(p1);
        p2 = dpp_add<DPP_ROR4>(p2); p3 = dpp_add<DPP_ROR4>(p3);
        if (pc == 0) {
            float4 o;
            o.x = -L2E * (p0 + pb0);
            o.y = -L2E * (p1 + pb1);
            o.z = -2.f * L2E * (p2 + pb2);
            o.w = -L2E * (p3 + pb3);
            gbuf[slot][ci][pg] = o;
        }
    };

    auto READR = [&](float4* R, int slot) {
        if (isl0) {
#pragma unroll
            for (int j = 0; j < PH; j++) R[j] = gbuf[slot][cidx][j];
        }
    };

    // Two independent LSTM steps (A and B chains), hand-interleaved so the
    // scheduler fills each chain's trans-latency with the other's issue.
    auto STEP2 = [&](float4 g, int s, int jm) {
        int t = s - l;
        bool active = (t >= 0) && (t < TT);

        float hinA = dpp_shr1(hA);
        float hinB = dpp_shr1(hB);
        float uA0 = fmaf(hA, wh0, fmaf(hinA, wi0, g.x));
        float uB0 = fmaf(hB, wh0, fmaf(hinB, wi0, g.x));
        float uA1 = fmaf(hA, wh1, fmaf(hinA, wi1, g.y));
        float uB1 = fmaf(hB, wh1, fmaf(hinB, wi1, g.y));
        float uA2 = fmaf(hA, wh2, fmaf(hinA, wi2, g.z));
        float uB2 = fmaf(hB, wh2, fmaf(hinB, wi2, g.z));
        float uA3 = fmaf(hA, wh3, fmaf(hinA, wi3, g.w));
        float uB3 = fmaf(hB, wh3, fmaf(hinB, wi3, g.w));

        float EA0 = fexp2(uA0), EB0 = fexp2(uB0);
        float EA1 = fexp2(uA1), EB1 = fexp2(uB1);
        float EA2 = fexp2(uA2), EB2 = fexp2(uB2);
        float EA3 = fexp2(uA3), EB3 = fexp2(uB3);
        float AA0 = 1.f + EA0, AB0 = 1.f + EB0;
        float AA1 = 1.f + EA1, AB1 = 1.f + EB1;
        float AA2 = 1.f + EA2, AB2 = 1.f + EB2;
        float AA3 = 1.f + EA3, AB3 = 1.f + EB3;

        float qA02 = frcp(AA0 * AA2);
        float qB02 = frcp(AB0 * AB2);
        float nA2  = fmaf(EA2, c2, -c2);
        float nB2  = fmaf(EB2, c2, -c2);
        float tmA  = nA2 * qA02;
        float tmB  = nB2 * qB02;
        float rA1  = frcp(AA1);
        float rB1  = frcp(AB1);
        float csnA = fmaf(csA, rA1, tmA);
        float csnB = fmaf(csB, rB1, tmB);
        csnA = fmed3(csnA, -88.f, 88.f);
        csnB = fmed3(csnB, -88.f, 88.f);
        float EcA = fexp2(csnA), EcB = fexp2(csnB);
        float AcA = 1.f + EcA,  AcB = 1.f + EcB;
        float qcA = frcp(AcA * AA3);
        float qcB = frcp(AcB * AB3);
        float hnA = (1.f - EcA) * qcA;
        float hnB = (1.f - EcB) * qcB;

        if (active) { csA = csnA; hA = hnA; csB = csnB; hB = hnB; }

        float hnS = rowA ? hnA : hnB;          // row-authoritative value
        if (jm == 1) o0 = hnS;
        else if (jm == 2) o1 = hnS;
        else if (jm == 3) o2 = hnS;
        else o3 = hnS;                          // jm == 0
        if (jm == 0 && s >= 12 && s <= 520 && isl9) {
            float4 v;
            v.x = 60.f * frcp(1.f + fexp2(-L2E * o0));
            v.y = 60.f * frcp(1.f + fexp2(-L2E * o1));
            v.z = 60.f * frcp(1.f + fexp2(-L2E * o2));
            v.w = 60.f * frcp(1.f + fexp2(-L2E * o3));
            *(float4*)(outp + (s - 12)) = v;
        }
    };

    float4 RA[PH], RB[PH];
    float4 bbv = make_float4(bb0, bb1, bb2, bb3);
#pragma unroll
    for (int i = 0; i < PH; i++) { RA[i] = bbv; RB[i] = bbv; }

    // prologue: VA<-ph0, VB<-ph1; produce ph0; regs<-ph0; VA<-ph2
    LOADV(VA0, VA1, VA2, VA3, 0);
    LOADV(VB0, VB1, VB2, VB3, 1);
    PROD1(VA0, 0, 0); PROD1(VA1, 1, 0); PROD1(VA2, 2, 0); PROD1(VA3, 3, 0);
    READR(RA, 0);
    LOADV(VA0, VA1, VA2, VA3, 2);

    // steady state: at top RA=regs(ph p), VB=x(ph p+1), VA=x(ph p+2)
    for (int p = 0; p < PHASES; p += 2) {
        PROD1(VB0, 0, 1); PROD1(VB1, 1, 1); PROD1(VB2, 2, 1); PROD1(VB3, 3, 1);
#pragma unroll
        for (int j = 0; j < PH; j++) STEP2(RA[j], p * PH + j, j & 3);
        READR(RB, 1);                                  // regs <- ph p+1
        LOADV(VB0, VB1, VB2, VB3, p + 3);

        PROD1(VA0, 0, 0); PROD1(VA1, 1, 0); PROD1(VA2, 2, 0); PROD1(VA3, 3, 0);
#pragma unroll
        for (int j = 0; j < PH; j++) STEP2(RB[j], (p + 1) * PH + j, j & 3);
        READR(RA, 0);                                  // regs <- ph p+2
        LOADV(VA0, VA1, VA2, VA3, p + 4);
    }
}

extern "C" void kernel_launch(void* const* d_in, const int* in_sizes, int n_in,
                              void* d_out, int out_size, void* d_ws, size_t ws_size,
                              hipStream_t stream)
{
    const float* x    = (const float*)d_in[0];
    const float* Wih0 = (const float*)d_in[1];
    const float* Whh0 = (const float*)d_in[2];
    const float* b0   = (const float*)d_in[3];
    const float* Wihr = (const float*)d_in[4];
    const float* Whhr = (const float*)d_in[5];
    const float* br   = (const float*)d_in[6];
    float* out = (float*)d_out;

    k_fused<<<BB / CPB, 64, 0, stream>>>(x, Wih0, Whh0, b0, Wihr, Whhr, br, out);
}

// Round 13
// 108.884 us; speedup vs baseline: 1.1321x; 1.1321x over previous
//
#include <hip/hip_runtime.h>

#define BB 4096   // batch
#define TT 512    // time steps
#define DD 32     // input dim
#define NL 10     // layers
#define PH 8      // steps per phase
#define PHASES 66 // 528 steps
#define CPB 4     // chains per block (1024 blocks, 1 wave/SIMD)

static constexpr float L2E = 1.4426950408889634f;   // log2(e)
static constexpr float CLM = 3.2f;                  // Pade validity clamp

typedef float f4 __attribute__((ext_vector_type(4)));

__device__ __forceinline__ float fexp2(float x) { return __builtin_amdgcn_exp2f(x); }
__device__ __forceinline__ float frcp(float x)  { return __builtin_amdgcn_rcpf(x); }
__device__ __forceinline__ float fmed3(float x, float a, float b) {
    return __builtin_amdgcn_fmed3f(x, a, b);
}

// row_shr:1 within each 16-lane row; row-lane 0 gets 0 (bound_ctrl).
__device__ __forceinline__ float dpp_shr1(float x) {
    int r = __builtin_amdgcn_update_dpp(0, __float_as_int(x), 0x111, 0xF, 0xF, true);
    return __int_as_float(r);
}

template<int CTRL>
__device__ __forceinline__ float dpp_add(float x) {
    return x + __int_as_float(__builtin_amdgcn_update_dpp(
        0, __float_as_int(x), CTRL, 0xF, 0xF, true));
}
#define DPP_XOR1 0xB1   // quad_perm [1,0,3,2]
#define DPP_XOR2 0x4E   // quad_perm [2,3,0,1]
#define DPP_ROR4 0x124  // row_ror:4 cross-quad gather

// Pade[5/4] tanh(u), |u|<=3.2 (pre-clamped): 7 VALU + 1 rcp, NO exp2.
__device__ __forceinline__ float pade_t(float u) {
    float x2 = u * u;
    float pn = fmaf(x2, fmaf(x2, 1.0f, 105.f), 945.f);
    float pd = fmaf(x2, fmaf(x2, 15.f, 420.f), 945.f);
    return (u * pn) * frcp(pd);
}
// sigmoid(2u) = 0.5 + 0.5*tanh(u): 0.5 folded into numerator coeffs.
__device__ __forceinline__ float pade_s(float u) {
    float x2 = u * u;
    float pn = fmaf(x2, fmaf(x2, 0.5f, 52.5f), 472.5f);
    float pd = fmaf(x2, fmaf(x2, 15.f, 420.f), 945.f);
    return fmaf(u * pn, frcp(pd), 0.5f);
}

// ---------------------------------------------------------------------------
// R13 = R10 structure, Pade-rational gate math (5 trans/step instead of 8,
// no exp2 on the serial chain), raw-h stores + sigma deferred to epilogue.
// Weights for sigma gates (0,1,3) pre-scaled by 0.5; tanh gate (2) by 1.
// ---------------------------------------------------------------------------
__global__ __launch_bounds__(64) void k_fused(
    const float* __restrict__ x, const float* __restrict__ Wih0,
    const float* __restrict__ Whh0, const float* __restrict__ b0,
    const float* __restrict__ Wihr, const float* __restrict__ Whhr,
    const float* __restrict__ br, float* __restrict__ out)
{
    __shared__ float4 gbuf[2][CPB][PH + 1];   // [slot][chain][step], +1 pad

    const int lane = threadIdx.x & 63;
    const int blk  = blockIdx.x;

    // ---- producer-role constants ----
    const int pg = lane >> 3;               // step-in-phase this lane helps produce
    const int pc = lane & 7;                // float4 chunk of the 32-wide x row
    const f4 pw0 = *(const f4*)(Wih0 + 0 * DD + pc * 4);
    const f4 pw1 = *(const f4*)(Wih0 + 1 * DD + pc * 4);
    const f4 pw2 = *(const f4*)(Wih0 + 2 * DD + pc * 4);
    const f4 pw3 = *(const f4*)(Wih0 + 3 * DD + pc * 4);
    const float pb0 = b0[0], pb1 = b0[1], pb2 = b0[2], pb3 = b0[3];

    // ---- consumer-role constants ----
    const int cidx = lane >> 4;             // row = chain-in-block
    const int l = lane & 15;                // 0..9 live layers
    const int chain = blk * CPB + cidx;
    const float sk0 = 0.5f, sk1 = 0.5f, sk2 = 1.0f, sk3 = 0.5f;
    const bool isl0 = (l == 0), isl9 = (l == NL - 1);
    const int li = (l >= 1 && l <= 9) ? (l - 1) : 0;

    float wi0 = 0, wi1 = 0, wi2 = 0, wi3 = 0;
    float wh0, wh1, wh2, wh3;
    float bb0 = 0, bb1 = 0, bb2 = 0, bb3 = 0;
    if (isl0) {
        wh0 = sk0 * Whh0[0]; wh1 = sk1 * Whh0[1];
        wh2 = sk2 * Whh0[2]; wh3 = sk3 * Whh0[3];
    } else {
        const float* pi = Wihr + li * 4;
        const float* ph = Whhr + li * 4;
        const float* pb = br   + li * 4;
        wi0 = sk0 * pi[0]; wi1 = sk1 * pi[1]; wi2 = sk2 * pi[2]; wi3 = sk3 * pi[3];
        wh0 = sk0 * ph[0]; wh1 = sk1 * ph[1]; wh2 = sk2 * ph[2]; wh3 = sk3 * ph[3];
        bb0 = sk0 * pb[0]; bb1 = sk1 * pb[1]; bb2 = sk2 * pb[2]; bb3 = sk3 * pb[3];
    }

    float* outp = out + (size_t)chain * TT;
    float h = 0.f, cs = 0.f;
    float o0 = 0.f, o1 = 0.f, o2 = 0.f, o3 = 0.f;

    const float* xb = x + (size_t)blk * CPB * TT * DD;

    f4 VA0, VA1, VA2, VA3, VB0, VB1, VB2, VB3;

    auto LOADV = [&](f4& v0, f4& v1, f4& v2, f4& v3, int p) {
        int t = p * PH + pg; t = t < TT ? t : TT - 1;   // tail clamps (discarded)
        const float* base = xb + (size_t)t * DD + pc * 4;
        v0 = __builtin_nontemporal_load((const f4*)(base + 0 * TT * DD));
        v1 = __builtin_nontemporal_load((const f4*)(base + 1 * TT * DD));
        v2 = __builtin_nontemporal_load((const f4*)(base + 2 * TT * DD));
        v3 = __builtin_nontemporal_load((const f4*)(base + 3 * TT * DD));
    };

    auto PROD1 = [&](const f4 v, int ci, int slot) {    // ci, slot literal at call site
        float p0 = v.x * pw0.x + v.y * pw0.y + v.z * pw0.z + v.w * pw0.w;
        float p1 = v.x * pw1.x + v.y * pw1.y + v.z * pw1.z + v.w * pw1.w;
        float p2 = v.x * pw2.x + v.y * pw2.y + v.z * pw2.z + v.w * pw2.w;
        float p3 = v.x * pw3.x + v.y * pw3.y + v.z * pw3.z + v.w * pw3.w;
        p0 = dpp_add<DPP_XOR1>(p0); p1 = dpp_add<DPP_XOR1>(p1);
        p2 = dpp_add<DPP_XOR1>(p2); p3 = dpp_add<DPP_XOR1>(p3);
        p0 = dpp_add<DPP_XOR2>(p0); p1 = dpp_add<DPP_XOR2>(p1);
        p2 = dpp_add<DPP_XOR2>(p2); p3 = dpp_add<DPP_XOR2>(p3);
        p0 = dpp_add<DPP_ROR4>(p0); p1 = dpp_add<DPP_ROR4>(p1);
        p2 = dpp_add<DPP_ROR4>(p2); p3 = dpp_add<DPP_ROR4>(p3);
        if (pc == 0) {
            float4 o;
            o.x = 0.5f * (p0 + pb0);     // sigma gates: 0.5 prescale
            o.y = 0.5f * (p1 + pb1);
            o.z =        (p2 + pb2);     // tanh gate: natural scale
            o.w = 0.5f * (p3 + pb3);
            gbuf[slot][ci][pg] = o;
        }
    };

    auto READR = [&](float4* R, int slot) {
        if (isl0) {
#pragma unroll
            for (int j = 0; j < PH; j++) R[j] = gbuf[slot][cidx][j];
        }
    };

    auto STEP = [&](float4 g, int s, int jm) {
        int t = s - l;
        bool active = (t >= 0) && (t < TT);

        float hin = dpp_shr1(h);                      // h_{l-1}(t)
        float u0 = fmaf(h, wh0, fmaf(hin, wi0, g.x));
        float u1 = fmaf(h, wh1, fmaf(hin, wi1, g.y));
        float u2 = fmaf(h, wh2, fmaf(hin, wi2, g.z));
        float u3 = fmaf(h, wh3, fmaf(hin, wi3, g.w));
        u0 = fmed3(u0, -CLM, CLM);
        u1 = fmed3(u1, -CLM, CLM);
        u2 = fmed3(u2, -CLM, CLM);
        u3 = fmed3(u3, -CLM, CLM);

        float i_ = pade_s(u0);
        float f_ = pade_s(u1);
        float g_ = pade_t(u2);
        float o_ = pade_s(u3);
        float cn = fmaf(f_, cs, i_ * g_);
        float mc = fmed3(cn, -CLM, CLM);
        float th = pade_t(mc);
        float hn = o_ * th;

        if (active) { cs = cn; h = hn; }

        if (jm == 1) o0 = hn;
        else if (jm == 2) o1 = hn;
        else if (jm == 3) o2 = hn;
        else o3 = hn;                                  // jm == 0
        if (jm == 0 && s >= 12 && s <= 520 && isl9) {
            float4 v;
            v.x = o0; v.y = o1; v.z = o2; v.w = o3;    // RAW h; sigma in epilogue
            *(float4*)(outp + (s - 12)) = v;
        }
    };

    float4 RA[PH], RB[PH];
    float4 bbv = make_float4(bb0, bb1, bb2, bb3);
#pragma unroll
    for (int i = 0; i < PH; i++) { RA[i] = bbv; RB[i] = bbv; }

    // prologue: VA<-ph0, VB<-ph1; produce ph0; regs<-ph0; VA<-ph2
    LOADV(VA0, VA1, VA2, VA3, 0);
    LOADV(VB0, VB1, VB2, VB3, 1);
    PROD1(VA0, 0, 0); PROD1(VA1, 1, 0); PROD1(VA2, 2, 0); PROD1(VA3, 3, 0);
    READR(RA, 0);
    LOADV(VA0, VA1, VA2, VA3, 2);

    // steady state: at top RA=regs(ph p), VB=x(ph p+1), VA=x(ph p+2)
    for (int p = 0; p < PHASES; p += 2) {
        PROD1(VB0, 0, 1); PROD1(VB1, 1, 1); PROD1(VB2, 2, 1); PROD1(VB3, 3, 1);
#pragma unroll
        for (int j = 0; j < PH; j++) STEP(RA[j], p * PH + j, j & 3);
        READR(RB, 1);                                  // regs <- ph p+1
        LOADV(VB0, VB1, VB2, VB3, p + 3);

        PROD1(VA0, 0, 0); PROD1(VA1, 1, 0); PROD1(VA2, 2, 0); PROD1(VA3, 3, 0);
#pragma unroll
        for (int j = 0; j < PH; j++) STEP(RB[j], (p + 1) * PH + j, j & 3);
        READR(RA, 0);                                  // regs <- ph p+2
        LOADV(VA0, VA1, VA2, VA3, p + 4);
    }
}

// Epilogue: out = 60 * sigmoid(out), in-place, float4, memory-bound (~4 us).
__global__ __launch_bounds__(256) void k_sig(float* __restrict__ out)
{
    int i = blockIdx.x * 256 + threadIdx.x;            // 524288 float4s
    float4 v = ((float4*)out)[i];
    v.x = 60.f * frcp(1.f + fexp2(-L2E * v.x));
    v.y = 60.f * frcp(1.f + fexp2(-L2E * v.y));
    v.z = 60.f * frcp(1.f + fexp2(-L2E * v.z));
    v.w = 60.f * frcp(1.f + fexp2(-L2E * v.w));
    ((float4*)out)[i] = v;
}

extern "C" void kernel_launch(void* const* d_in, const int* in_sizes, int n_in,
                              void* d_out, int out_size, void* d_ws, size_t ws_size,
                              hipStream_t stream)
{
    const float* x    = (const float*)d_in[0];
    const float* Wih0 = (const float*)d_in[1];
    const float* Whh0 = (const float*)d_in[2];
    const float* b0   = (const float*)d_in[3];
    const float* Wihr = (const float*)d_in[4];
    const float* Whhr = (const float*)d_in[5];
    const float* br   = (const float*)d_in[6];
    float* out = (float*)d_out;

    k_fused<<<BB / CPB, 64, 0, stream>>>(x, Wih0, Whh0, b0, Wihr, Whhr, br, out);
    k_sig<<<(BB * TT / 4) / 256, 256, 0, stream>>>(out);
}

// Round 14
// 104.148 us; speedup vs baseline: 1.1836x; 1.0455x over previous
//
#include <hip/hip_runtime.h>

#define BB 4096   // batch
#define TT 512    // time steps
#define DD 32     // input dim
#define NL 10     // layers
#define PH 8      // steps per phase
#define PHASES 66 // consumer phases (528 steps)
#define PPH 68    // produced phases (2 junk tail phases for prefetch reads)
#define RING 4    // LDS ring slots
#define CPB 4     // chains per block

static constexpr float L2E = 1.4426950408889634f;   // log2(e)

typedef float f4 __attribute__((ext_vector_type(4)));

__device__ __forceinline__ float fexp2(float x) { return __builtin_amdgcn_exp2f(x); }
__device__ __forceinline__ float frcp(float x)  { return __builtin_amdgcn_rcpf(x); }
__device__ __forceinline__ float fmed3(float x, float a, float b) {
    return __builtin_amdgcn_fmed3f(x, a, b);
}

// row_shr:1 within each 16-lane row; row-lane 0 gets 0 (bound_ctrl).
__device__ __forceinline__ float dpp_shr1(float x) {
    int r = __builtin_amdgcn_update_dpp(0, __float_as_int(x), 0x111, 0xF, 0xF, true);
    return __int_as_float(r);
}

template<int CTRL>
__device__ __forceinline__ float dpp_add(float x) {
    return x + __int_as_float(__builtin_amdgcn_update_dpp(
        0, __float_as_int(x), CTRL, 0xF, 0xF, true));
}
#define DPP_XOR1 0xB1   // quad_perm [1,0,3,2]
#define DPP_XOR2 0x4E   // quad_perm [2,3,0,1]
#define DPP_ROR4 0x124  // row_ror:4 cross-quad gather (verified R10)

// ---------------------------------------------------------------------------
// R14: two-wave producer/consumer, lock-free LDS ring (NO barriers after init).
//  wave 0 = R10's consumer verbatim: 4 chains x 16-lane rows, DPP handoff,
//           reg ring RA/RB <- LDS ring slot (p % 4), exp2-form STEP.
//  wave 1 = R10's producer verbatim: nt x-loads, DPP 8-lane reduce,
//           writes slot (q % 4), runs <= RING phases ahead.
//  Handshake: monotonic counters prod_ct / cons_ct in LDS, s_sleep polling;
//  producer publishes only after lgkmcnt(0) (data visible before flag).
// ---------------------------------------------------------------------------
__global__ __launch_bounds__(128) void k_fused(
    const float* __restrict__ x, const float* __restrict__ Wih0,
    const float* __restrict__ Whh0, const float* __restrict__ b0,
    const float* __restrict__ Wihr, const float* __restrict__ Whhr,
    const float* __restrict__ br, float* __restrict__ out)
{
    __shared__ float4 gbuf[RING][CPB][PH + 1];   // [slot][chain][step], +1 pad
    __shared__ int prod_ct;                       // phases produced
    __shared__ int cons_ct;                       // phases consumed (READR done)

    const int tid  = threadIdx.x;
    const int wave = tid >> 6;
    const int lane = tid & 63;
    const int blk  = blockIdx.x;

    if (tid == 0) { prod_ct = 0; cons_ct = 0; }
    __syncthreads();                              // once; init visibility

    volatile int* vprod = &prod_ct;
    volatile int* vcons = &cons_ct;

    if (wave == 1) {
        // ========================= producer =========================
        const int pg = lane >> 3;                 // step-in-phase
        const int pc = lane & 7;                  // float4 chunk of row
        const f4 pw0 = *(const f4*)(Wih0 + 0 * DD + pc * 4);
        const f4 pw1 = *(const f4*)(Wih0 + 1 * DD + pc * 4);
        const f4 pw2 = *(const f4*)(Wih0 + 2 * DD + pc * 4);
        const f4 pw3 = *(const f4*)(Wih0 + 3 * DD + pc * 4);
        const float pb0 = b0[0], pb1 = b0[1], pb2 = b0[2], pb3 = b0[3];
        const float* xb = x + (size_t)blk * CPB * TT * DD;

        f4 VA0, VA1, VA2, VA3, VB0, VB1, VB2, VB3;

        auto LOADV = [&](f4& v0, f4& v1, f4& v2, f4& v3, int p) {
            int t = p * PH + pg; t = t < TT ? t : TT - 1;
            const float* base = xb + (size_t)t * DD + pc * 4;
            v0 = __builtin_nontemporal_load((const f4*)(base + 0 * TT * DD));
            v1 = __builtin_nontemporal_load((const f4*)(base + 1 * TT * DD));
            v2 = __builtin_nontemporal_load((const f4*)(base + 2 * TT * DD));
            v3 = __builtin_nontemporal_load((const f4*)(base + 3 * TT * DD));
        };

        auto PROD1 = [&](const f4 v, int ci, int slot) {
            float p0 = v.x * pw0.x + v.y * pw0.y + v.z * pw0.z + v.w * pw0.w;
            float p1 = v.x * pw1.x + v.y * pw1.y + v.z * pw1.z + v.w * pw1.w;
            float p2 = v.x * pw2.x + v.y * pw2.y + v.z * pw2.z + v.w * pw2.w;
            float p3 = v.x * pw3.x + v.y * pw3.y + v.z * pw3.z + v.w * pw3.w;
            p0 = dpp_add<DPP_XOR1>(p0); p1 = dpp_add<DPP_XOR1>(p1);
            p2 = dpp_add<DPP_XOR1>(p2); p3 = dpp_add<DPP_XOR1>(p3);
            p0 = dpp_add<DPP_XOR2>(p0); p1 = dpp_add<DPP_XOR2>(p1);
            p2 = dpp_add<DPP_XOR2>(p2); p3 = dpp_add<DPP_XOR2>(p3);
            p0 = dpp_add<DPP_ROR4>(p0); p1 = dpp_add<DPP_ROR4>(p1);
            p2 = dpp_add<DPP_ROR4>(p2); p3 = dpp_add<DPP_ROR4>(p3);
            if (pc == 0) {
                float4 o;
                o.x = -L2E * (p0 + pb0);
                o.y = -L2E * (p1 + pb1);
                o.z = -2.f * L2E * (p2 + pb2);
                o.w = -L2E * (p3 + pb3);
                gbuf[slot][ci][pg] = o;
            }
        };

        auto waitcons = [&](int v) {
            while (*vcons < v) __builtin_amdgcn_s_sleep(8);
        };

        LOADV(VA0, VA1, VA2, VA3, 0);
        for (int q = 0; q < PPH; q += 2) {
            LOADV(VB0, VB1, VB2, VB3, q + 1);
            waitcons(q - (RING - 1));             // slot q%4 free
            PROD1(VA0, 0, q & 3); PROD1(VA1, 1, q & 3);
            PROD1(VA2, 2, q & 3); PROD1(VA3, 3, q & 3);
            asm volatile("s_waitcnt lgkmcnt(0)" ::: "memory");
            if (lane == 0) *vprod = q + 1;
            if (q + 2 < PPH) LOADV(VA0, VA1, VA2, VA3, q + 2);
            waitcons(q + 1 - (RING - 1));         // slot (q+1)%4 free
            PROD1(VB0, 0, (q + 1) & 3); PROD1(VB1, 1, (q + 1) & 3);
            PROD1(VB2, 2, (q + 1) & 3); PROD1(VB3, 3, (q + 1) & 3);
            asm volatile("s_waitcnt lgkmcnt(0)" ::: "memory");
            if (lane == 0) *vprod = q + 2;
        }
    } else {
        // ========================= consumer =========================
        const int cidx = lane >> 4;               // row = chain-in-block
        const int l = lane & 15;                  // 0..9 live layers
        const int chain = blk * CPB + cidx;
        const float sk0 = -L2E, sk1 = -L2E, sk2 = -2.f * L2E, sk3 = -L2E;
        const bool isl0 = (l == 0), isl9 = (l == NL - 1);
        const int li = (l >= 1 && l <= 9) ? (l - 1) : 0;

        float wi0 = 0, wi1 = 0, wi2 = 0, wi3 = 0;
        float wh0, wh1, wh2, wh3;
        float bb0 = 0, bb1 = 0, bb2 = 0, bb3 = 0;
        if (isl0) {
            wh0 = sk0 * Whh0[0]; wh1 = sk1 * Whh0[1];
            wh2 = sk2 * Whh0[2]; wh3 = sk3 * Whh0[3];
        } else {
            const float* pi = Wihr + li * 4;
            const float* ph = Whhr + li * 4;
            const float* pb = br   + li * 4;
            wi0 = sk0 * pi[0]; wi1 = sk1 * pi[1]; wi2 = sk2 * pi[2]; wi3 = sk3 * pi[3];
            wh0 = sk0 * ph[0]; wh1 = sk1 * ph[1]; wh2 = sk2 * ph[2]; wh3 = sk3 * ph[3];
            bb0 = sk0 * pb[0]; bb1 = sk1 * pb[1]; bb2 = sk2 * pb[2]; bb3 = sk3 * pb[3];
        }

        float* outp = out + (size_t)chain * TT;
        const float c2 = 2.f * L2E;
        float h = 0.f, cs = 0.f;                  // cs = -2*L2E*c
        float o0 = 0.f, o1 = 0.f, o2 = 0.f, o3 = 0.f;

        auto READR = [&](float4* R, int slot) {
            if (isl0) {
#pragma unroll
                for (int j = 0; j < PH; j++) R[j] = gbuf[slot][cidx][j];
            }
        };

        auto waitprod = [&](int v) {
            while (*vprod < v) __builtin_amdgcn_s_sleep(1);
        };

        auto STEP = [&](float4 g, int s, int jm) {
            int t = s - l;
            bool active = (t >= 0) && (t < TT);

            float hin = dpp_shr1(h);              // h_{l-1}(t)
            float u0 = fmaf(h, wh0, fmaf(hin, wi0, g.x));
            float u1 = fmaf(h, wh1, fmaf(hin, wi1, g.y));
            float u2 = fmaf(h, wh2, fmaf(hin, wi2, g.z));
            float u3 = fmaf(h, wh3, fmaf(hin, wi3, g.w));

            float E0 = fexp2(u0), E1 = fexp2(u1), E2 = fexp2(u2), E3 = fexp2(u3);
            float A0 = 1.f + E0, A1 = 1.f + E1, A2 = 1.f + E2, A3 = 1.f + E3;
            float q02  = frcp(A0 * A2);
            float num2 = fmaf(E2, c2, -c2);
            float term = num2 * q02;
            float r1   = frcp(A1);
            float csn  = fmaf(cs, r1, term);      // -2L2E*c_new
            csn = fmed3(csn, -88.f, 88.f);
            float Ec  = fexp2(csn);
            float Ac  = 1.f + Ec;
            float qc3 = frcp(Ac * A3);
            float hn  = (1.f - Ec) * qc3;

            if (active) { cs = csn; h = hn; }

            if (jm == 1) o0 = hn;
            else if (jm == 2) o1 = hn;
            else if (jm == 3) o2 = hn;
            else o3 = hn;                          // jm == 0
            if (jm == 0 && s >= 12 && s <= 520 && isl9) {
                float4 v;
                v.x = 60.f * frcp(1.f + fexp2(-L2E * o0));
                v.y = 60.f * frcp(1.f + fexp2(-L2E * o1));
                v.z = 60.f * frcp(1.f + fexp2(-L2E * o2));
                v.w = 60.f * frcp(1.f + fexp2(-L2E * o3));
                *(float4*)(outp + (s - 12)) = v;
            }
        };

        float4 RA[PH], RB[PH];
        float4 bbv = make_float4(bb0, bb1, bb2, bb3);
#pragma unroll
        for (int i = 0; i < PH; i++) { RA[i] = bbv; RB[i] = bbv; }

        waitprod(1);
        READR(RA, 0);
        asm volatile("s_waitcnt lgkmcnt(0)" ::: "memory");
        if (lane == 0) *vcons = 1;

        for (int p = 0; p < PHASES; p += 2) {
#pragma unroll
            for (int j = 0; j < PH; j++) STEP(RA[j], p * PH + j, j & 3);
            waitprod(p + 2);
            READR(RB, (p + 1) & 3);               // regs <- phase p+1
            asm volatile("s_waitcnt lgkmcnt(0)" ::: "memory");
            if (lane == 0) *vcons = p + 2;
#pragma unroll
            for (int j = 0; j < PH; j++) STEP(RB[j], (p + 1) * PH + j, j & 3);
            waitprod(p + 3);
            READR(RA, (p + 2) & 3);               // regs <- phase p+2
            asm volatile("s_waitcnt lgkmcnt(0)" ::: "memory");
            if (lane == 0) *vcons = p + 3;
        }
    }
}

extern "C" void kernel_launch(void* const* d_in, const int* in_sizes, int n_in,
                              void* d_out, int out_size, void* d_ws, size_t ws_size,
                              hipStream_t stream)
{
    const float* x    = (const float*)d_in[0];
    const float* Wih0 = (const float*)d_in[1];
    const float* Whh0 = (const float*)d_in[2];
    const float* b0   = (const float*)d_in[3];
    const float* Wihr = (const float*)d_in[4];
    const float* Whhr = (const float*)d_in[5];
    const float* br   = (const float*)d_in[6];
    float* out = (float*)d_out;

    k_fused<<<BB / CPB, 128, 0, stream>>>(x, Wih0, Whh0, b0, Wihr, Whhr, br, out);
}

// Round 15
// 90.748 us; speedup vs baseline: 1.3584x; 1.1477x over previous
//
#include <hip/hip_runtime.h>

#define BB 4096   // batch
#define TT 512    // time steps
#define DD 32     // input dim
#define NL 10     // layers
#define PH 8      // steps per phase
#define PHASES 66 // 528 steps
#define CPB 4     // chains per block (1024 blocks, 1 wave/SIMD)

static constexpr float L2E = 1.4426950408889634f;   // log2(e)
static constexpr float GCL = 26.0f;                 // producer g-clamp (scaled)

typedef float f4 __attribute__((ext_vector_type(4)));

__device__ __forceinline__ float fexp2(float x) { return __builtin_amdgcn_exp2f(x); }
__device__ __forceinline__ float frcp(float x)  { return __builtin_amdgcn_rcpf(x); }
__device__ __forceinline__ float fmed3(float x, float a, float b) {
    return __builtin_amdgcn_fmed3f(x, a, b);
}

// row_shr:1 within each 16-lane row; row-lane 0 gets 0 (bound_ctrl).
__device__ __forceinline__ float dpp_shr1(float x) {
    int r = __builtin_amdgcn_update_dpp(0, __float_as_int(x), 0x111, 0xF, 0xF, true);
    return __int_as_float(r);
}

template<int CTRL>
__device__ __forceinline__ float dpp_add(float x) {
    return x + __int_as_float(__builtin_amdgcn_update_dpp(
        0, __float_as_int(x), CTRL, 0xF, 0xF, true));
}
#define DPP_XOR1 0xB1   // quad_perm [1,0,3,2]
#define DPP_XOR2 0x4E   // quad_perm [2,3,0,1]
#define DPP_ROR4 0x124  // row_ror:4 cross-quad gather (verified R10)

// ---------------------------------------------------------------------------
// R15 = R10 skeleton + trans-diet STEP:
//   c_new = [c*A0A2 + (1-E2)*A1] * rcp(A0*A1*A2)     (one rcp, was two)
//   h_new = (mc*pn) * rcp(pd*A3), Pade[5/4] tanh     (no Ec exp2)
//   60*sigmoid deferred to epilogue k_sig            (store raw h)
// Producer clamps g at +-26 (scaled) so A-products can't overflow fp32.
// Trans/step: 4 exp2 + 2 rcp (was ~9 incl. output sigma).
// ---------------------------------------------------------------------------
__global__ __launch_bounds__(64) void k_fused(
    const float* __restrict__ x, const float* __restrict__ Wih0,
    const float* __restrict__ Whh0, const float* __restrict__ b0,
    const float* __restrict__ Wihr, const float* __restrict__ Whhr,
    const float* __restrict__ br, float* __restrict__ out)
{
    __shared__ float4 gbuf[2][CPB][PH + 1];   // [slot][chain][step], +1 pad

    const int lane = threadIdx.x & 63;
    const int blk  = blockIdx.x;

    // ---- producer-role constants ----
    const int pg = lane >> 3;               // step-in-phase this lane helps produce
    const int pc = lane & 7;                // float4 chunk of the 32-wide x row
    const f4 pw0 = *(const f4*)(Wih0 + 0 * DD + pc * 4);
    const f4 pw1 = *(const f4*)(Wih0 + 1 * DD + pc * 4);
    const f4 pw2 = *(const f4*)(Wih0 + 2 * DD + pc * 4);
    const f4 pw3 = *(const f4*)(Wih0 + 3 * DD + pc * 4);
    const float pb0 = b0[0], pb1 = b0[1], pb2 = b0[2], pb3 = b0[3];

    // ---- consumer-role constants ----
    const int cidx = lane >> 4;             // row = chain-in-block
    const int l = lane & 15;                // 0..9 live layers
    const int chain = blk * CPB + cidx;
    const float sk0 = -L2E, sk1 = -L2E, sk2 = -2.f * L2E, sk3 = -L2E;
    const bool isl0 = (l == 0), isl9 = (l == NL - 1);
    const int li = (l >= 1 && l <= 9) ? (l - 1) : 0;

    float wi0 = 0, wi1 = 0, wi2 = 0, wi3 = 0;
    float wh0, wh1, wh2, wh3;
    float bb0 = 0, bb1 = 0, bb2 = 0, bb3 = 0;
    if (isl0) {
        wh0 = sk0 * Whh0[0]; wh1 = sk1 * Whh0[1];
        wh2 = sk2 * Whh0[2]; wh3 = sk3 * Whh0[3];
    } else {
        const float* pi = Wihr + li * 4;
        const float* ph = Whhr + li * 4;
        const float* pb = br   + li * 4;
        wi0 = sk0 * pi[0]; wi1 = sk1 * pi[1]; wi2 = sk2 * pi[2]; wi3 = sk3 * pi[3];
        wh0 = sk0 * ph[0]; wh1 = sk1 * ph[1]; wh2 = sk2 * ph[2]; wh3 = sk3 * ph[3];
        bb0 = sk0 * pb[0]; bb1 = sk1 * pb[1]; bb2 = sk2 * pb[2]; bb3 = sk3 * pb[3];
    }

    float* outp = out + (size_t)chain * TT;
    float h = 0.f, cs = 0.f;                // c in natural units now
    float o0 = 0.f, o1 = 0.f, o2 = 0.f, o3 = 0.f;

    const float* xb = x + (size_t)blk * CPB * TT * DD;

    f4 VA0, VA1, VA2, VA3, VB0, VB1, VB2, VB3;

    auto LOADV = [&](f4& v0, f4& v1, f4& v2, f4& v3, int p) {
        int t = p * PH + pg; t = t < TT ? t : TT - 1;   // tail clamps (discarded)
        const float* base = xb + (size_t)t * DD + pc * 4;
        v0 = __builtin_nontemporal_load((const f4*)(base + 0 * TT * DD));
        v1 = __builtin_nontemporal_load((const f4*)(base + 1 * TT * DD));
        v2 = __builtin_nontemporal_load((const f4*)(base + 2 * TT * DD));
        v3 = __builtin_nontemporal_load((const f4*)(base + 3 * TT * DD));
    };

    auto PROD1 = [&](const f4 v, int ci, int slot) {    // ci, slot literal at call site
        float p0 = v.x * pw0.x + v.y * pw0.y + v.z * pw0.z + v.w * pw0.w;
        float p1 = v.x * pw1.x + v.y * pw1.y + v.z * pw1.z + v.w * pw1.w;
        float p2 = v.x * pw2.x + v.y * pw2.y + v.z * pw2.z + v.w * pw2.w;
        float p3 = v.x * pw3.x + v.y * pw3.y + v.z * pw3.z + v.w * pw3.w;
        p0 = dpp_add<DPP_XOR1>(p0); p1 = dpp_add<DPP_XOR1>(p1);
        p2 = dpp_add<DPP_XOR1>(p2); p3 = dpp_add<DPP_XOR1>(p3);
        p0 = dpp_add<DPP_XOR2>(p0); p1 = dpp_add<DPP_XOR2>(p1);
        p2 = dpp_add<DPP_XOR2>(p2); p3 = dpp_add<DPP_XOR2>(p3);
        p0 = dpp_add<DPP_ROR4>(p0); p1 = dpp_add<DPP_ROR4>(p1);
        p2 = dpp_add<DPP_ROR4>(p2); p3 = dpp_add<DPP_ROR4>(p3);
        if (pc == 0) {
            float4 o;
            o.x = fmed3(-L2E * (p0 + pb0), -GCL, GCL);       // overflow guard
            o.y = fmed3(-L2E * (p1 + pb1), -GCL, GCL);
            o.z = fmed3(-2.f * L2E * (p2 + pb2), -GCL, GCL);
            o.w = fmed3(-L2E * (p3 + pb3), -GCL, GCL);
            gbuf[slot][ci][pg] = o;
        }
    };

    auto READR = [&](float4* R, int slot) {
        if (isl0) {
#pragma unroll
            for (int j = 0; j < PH; j++) R[j] = gbuf[slot][cidx][j];
        }
    };

    auto STEP = [&](float4 g, int s, int jm) {
        int t = s - l;
        bool active = (t >= 0) && (t < TT);

        float hin = dpp_shr1(h);                      // h_{l-1}(t)
        float u0 = fmaf(h, wh0, fmaf(hin, wi0, g.x)); // -L2E*a   (i gate)
        float u1 = fmaf(h, wh1, fmaf(hin, wi1, g.y)); // -L2E*b   (f gate)
        float u2 = fmaf(h, wh2, fmaf(hin, wi2, g.z)); // -2L2E*cb (g gate)
        float u3 = fmaf(h, wh3, fmaf(hin, wi3, g.w)); // -L2E*d   (o gate)

        float E0 = fexp2(u0), E1 = fexp2(u1), E2 = fexp2(u2), E3 = fexp2(u3);
        float A0 = 1.f + E0, A1 = 1.f + E1, A2 = 1.f + E2, A3 = 1.f + E3;
        float M1 = A0 * A2;
        float M2 = M1 * A1;
        float R  = frcp(M2);                          // one rcp for c-update
        float SA = (1.f - E2) * A1;                   // i*g~ numerator * A1
        float N  = fmaf(cs, M1, SA);
        float cn = N * R;                             // c_new = c/A1 + (1-E2)/(A0*A2)
        float mc = fmed3(cn, -3.2f, 3.2f);            // Pade validity window
        float x2 = mc * mc;
        float pn = fmaf(x2, fmaf(x2, 1.0f, 105.f), 945.f);
        float pd = fmaf(x2, fmaf(x2, 15.f, 420.f), 945.f);
        float RQ = frcp(pd * A3);                     // tanh-den and o-gate fused
        float hn = (mc * pn) * RQ;                    // h_new = o * tanh(c_new)

        if (active) { cs = cn; h = hn; }

        if (jm == 1) o0 = hn;
        else if (jm == 2) o1 = hn;
        else if (jm == 3) o2 = hn;
        else o3 = hn;                                  // jm == 0
        if (jm == 0 && s >= 12 && s <= 520 && isl9) {
            float4 v;
            v.x = o0; v.y = o1; v.z = o2; v.w = o3;    // RAW h; sigma in epilogue
            *(float4*)(outp + (s - 12)) = v;
        }
    };

    float4 RA[PH], RB[PH];
    float4 bbv = make_float4(bb0, bb1, bb2, bb3);
#pragma unroll
    for (int i = 0; i < PH; i++) { RA[i] = bbv; RB[i] = bbv; }

    // prologue: VA<-ph0, VB<-ph1; produce ph0; regs<-ph0; VA<-ph2
    LOADV(VA0, VA1, VA2, VA3, 0);
    LOADV(VB0, VB1, VB2, VB3, 1);
    PROD1(VA0, 0, 0); PROD1(VA1, 1, 0); PROD1(VA2, 2, 0); PROD1(VA3, 3, 0);
    READR(RA, 0);
    LOADV(VA0, VA1, VA2, VA3, 2);

    // steady state: at top RA=regs(ph p), VB=x(ph p+1), VA=x(ph p+2)
    for (int p = 0; p < PHASES; p += 2) {
        PROD1(VB0, 0, 1); PROD1(VB1, 1, 1); PROD1(VB2, 2, 1); PROD1(VB3, 3, 1);
#pragma unroll
        for (int j = 0; j < PH; j++) STEP(RA[j], p * PH + j, j & 3);
        READR(RB, 1);                                  // regs <- ph p+1
        LOADV(VB0, VB1, VB2, VB3, p + 3);

        PROD1(VA0, 0, 0); PROD1(VA1, 1, 0); PROD1(VA2, 2, 0); PROD1(VA3, 3, 0);
#pragma unroll
        for (int j = 0; j < PH; j++) STEP(RB[j], (p + 1) * PH + j, j & 3);
        READR(RA, 0);                                  // regs <- ph p+2
        LOADV(VA0, VA1, VA2, VA3, p + 4);
    }
}

// Epilogue: out = 60 * sigmoid(out), in-place, float4, memory-bound (~2.5 us).
__global__ __launch_bounds__(256) void k_sig(float* __restrict__ out)
{
    int i = blockIdx.x * 256 + threadIdx.x;            // 524288 float4s
    float4 v = ((float4*)out)[i];
    v.x = 60.f * frcp(1.f + fexp2(-L2E * v.x));
    v.y = 60.f * frcp(1.f + fexp2(-L2E * v.y));
    v.z = 60.f * frcp(1.f + fexp2(-L2E * v.z));
    v.w = 60.f * frcp(1.f + fexp2(-L2E * v.w));
    ((float4*)out)[i] = v;
}

extern "C" void kernel_launch(void* const* d_in, const int* in_sizes, int n_in,
                              void* d_out, int out_size, void* d_ws, size_t ws_size,
                              hipStream_t stream)
{
    const float* x    = (const float*)d_in[0];
    const float* Wih0 = (const float*)d_in[1];
    const float* Whh0 = (const float*)d_in[2];
    const float* b0   = (const float*)d_in[3];
    const float* Wihr = (const float*)d_in[4];
    const float* Whhr = (const float*)d_in[5];
    const float* br   = (const float*)d_in[6];
    float* out = (float*)d_out;

    k_fused<<<BB / CPB, 64, 0, stream>>>(x, Wih0, Whh0, b0, Wihr, Whhr, br, out);
    k_sig<<<(BB * TT / 4) / 256, 256, 0, stream>>>(out);
}

// Round 16
// 86.205 us; speedup vs baseline: 1.4300x; 1.0527x over previous
//
#include <hip/hip_runtime.h>

#define BB 4096   // batch
#define TT 512    // time steps
#define DD 32     // input dim
#define NL 10     // layers
#define PH 8      // steps per phase
#define PHASES 66 // 528 steps
#define CPB 4     // chains per block (1024 blocks, 1 wave/SIMD)

static constexpr float L2E = 1.4426950408889634f;   // log2(e)
static constexpr float GCL = 26.0f;                 // producer g-clamp (scaled)

typedef float f4 __attribute__((ext_vector_type(4)));
typedef float f2 __attribute__((ext_vector_type(2)));

__device__ __forceinline__ float fexp2(float x) { return __builtin_amdgcn_exp2f(x); }
__device__ __forceinline__ float frcp(float x)  { return __builtin_amdgcn_rcpf(x); }
__device__ __forceinline__ float fmed3(float x, float a, float b) {
    return __builtin_amdgcn_fmed3f(x, a, b);
}

// row_shr:1 within each 16-lane row; row-lane 0 gets 0 (bound_ctrl).
__device__ __forceinline__ float dpp_shr1(float x) {
    int r = __builtin_amdgcn_update_dpp(0, __float_as_int(x), 0x111, 0xF, 0xF, true);
    return __int_as_float(r);
}

template<int CTRL>
__device__ __forceinline__ float dpp_add(float x) {
    return x + __int_as_float(__builtin_amdgcn_update_dpp(
        0, __float_as_int(x), CTRL, 0xF, 0xF, true));
}
#define DPP_XOR1 0xB1   // quad_perm [1,0,3,2]
#define DPP_XOR2 0x4E   // quad_perm [2,3,0,1]
#define DPP_ROR4 0x124  // row_ror:4 cross-quad gather (verified R10)

// ---------------------------------------------------------------------------
// R16 = R15 skeleton with: inline output sigma (no epilogue kernel),
// pre-fma chain restructure (dpp runs parallel to h*wh+g), and float2
// packed gate math (v_pk_fma_f32 candidates). Producer unchanged.
// ---------------------------------------------------------------------------
__global__ __launch_bounds__(64) void k_fused(
    const float* __restrict__ x, const float* __restrict__ Wih0,
    const float* __restrict__ Whh0, const float* __restrict__ b0,
    const float* __restrict__ Wihr, const float* __restrict__ Whhr,
    const float* __restrict__ br, float* __restrict__ out)
{
    __shared__ float4 gbuf[2][CPB][PH + 1];   // [slot][chain][step], +1 pad

    const int lane = threadIdx.x & 63;
    const int blk  = blockIdx.x;

    // ---- producer-role constants ----
    const int pg = lane >> 3;               // step-in-phase this lane helps produce
    const int pc = lane & 7;                // float4 chunk of the 32-wide x row
    const f4 pw0 = *(const f4*)(Wih0 + 0 * DD + pc * 4);
    const f4 pw1 = *(const f4*)(Wih0 + 1 * DD + pc * 4);
    const f4 pw2 = *(const f4*)(Wih0 + 2 * DD + pc * 4);
    const f4 pw3 = *(const f4*)(Wih0 + 3 * DD + pc * 4);
    const float pb0 = b0[0], pb1 = b0[1], pb2 = b0[2], pb3 = b0[3];

    // ---- consumer-role constants ----
    const int cidx = lane >> 4;             // row = chain-in-block
    const int l = lane & 15;                // 0..9 live layers
    const int chain = blk * CPB + cidx;
    const float sk0 = -L2E, sk1 = -L2E, sk2 = -2.f * L2E, sk3 = -L2E;
    const bool isl0 = (l == 0), isl9 = (l == NL - 1);
    const int li = (l >= 1 && l <= 9) ? (l - 1) : 0;

    float wi0 = 0, wi1 = 0, wi2 = 0, wi3 = 0;
    float wh0, wh1, wh2, wh3;
    float bb0 = 0, bb1 = 0, bb2 = 0, bb3 = 0;
    if (isl0) {
        wh0 = sk0 * Whh0[0]; wh1 = sk1 * Whh0[1];
        wh2 = sk2 * Whh0[2]; wh3 = sk3 * Whh0[3];
    } else {
        const float* pi = Wihr + li * 4;
        const float* ph = Whhr + li * 4;
        const float* pb = br   + li * 4;
        wi0 = sk0 * pi[0]; wi1 = sk1 * pi[1]; wi2 = sk2 * pi[2]; wi3 = sk3 * pi[3];
        wh0 = sk0 * ph[0]; wh1 = sk1 * ph[1]; wh2 = sk2 * ph[2]; wh3 = sk3 * ph[3];
        bb0 = sk0 * pb[0]; bb1 = sk1 * pb[1]; bb2 = sk2 * pb[2]; bb3 = sk3 * pb[3];
    }

    // packed weight pairs for the gate math
    const f2 wi01 = {wi0, wi1}, wi23 = {wi2, wi3};
    const f2 wh01 = {wh0, wh1}, wh23 = {wh2, wh3};

    float* outp = out + (size_t)chain * TT;
    float h = 0.f, cs = 0.f;                // c in natural units
    float o0 = 0.f, o1 = 0.f, o2 = 0.f, o3 = 0.f;

    const float* xb = x + (size_t)blk * CPB * TT * DD;

    f4 VA0, VA1, VA2, VA3, VB0, VB1, VB2, VB3;

    auto LOADV = [&](f4& v0, f4& v1, f4& v2, f4& v3, int p) {
        int t = p * PH + pg; t = t < TT ? t : TT - 1;   // tail clamps (discarded)
        const float* base = xb + (size_t)t * DD + pc * 4;
        v0 = __builtin_nontemporal_load((const f4*)(base + 0 * TT * DD));
        v1 = __builtin_nontemporal_load((const f4*)(base + 1 * TT * DD));
        v2 = __builtin_nontemporal_load((const f4*)(base + 2 * TT * DD));
        v3 = __builtin_nontemporal_load((const f4*)(base + 3 * TT * DD));
    };

    auto PROD1 = [&](const f4 v, int ci, int slot) {    // ci, slot literal at call site
        float p0 = v.x * pw0.x + v.y * pw0.y + v.z * pw0.z + v.w * pw0.w;
        float p1 = v.x * pw1.x + v.y * pw1.y + v.z * pw1.z + v.w * pw1.w;
        float p2 = v.x * pw2.x + v.y * pw2.y + v.z * pw2.z + v.w * pw2.w;
        float p3 = v.x * pw3.x + v.y * pw3.y + v.z * pw3.z + v.w * pw3.w;
        p0 = dpp_add<DPP_XOR1>(p0); p1 = dpp_add<DPP_XOR1>(p1);
        p2 = dpp_add<DPP_XOR1>(p2); p3 = dpp_add<DPP_XOR1>(p3);
        p0 = dpp_add<DPP_XOR2>(p0); p1 = dpp_add<DPP_XOR2>(p1);
        p2 = dpp_add<DPP_XOR2>(p2); p3 = dpp_add<DPP_XOR2>(p3);
        p0 = dpp_add<DPP_ROR4>(p0); p1 = dpp_add<DPP_ROR4>(p1);
        p2 = dpp_add<DPP_ROR4>(p2); p3 = dpp_add<DPP_ROR4>(p3);
        if (pc == 0) {
            float4 o;
            o.x = fmed3(-L2E * (p0 + pb0), -GCL, GCL);       // overflow guard
            o.y = fmed3(-L2E * (p1 + pb1), -GCL, GCL);
            o.z = fmed3(-2.f * L2E * (p2 + pb2), -GCL, GCL);
            o.w = fmed3(-L2E * (p3 + pb3), -GCL, GCL);
            gbuf[slot][ci][pg] = o;
        }
    };

    auto READR = [&](float4* R, int slot) {
        if (isl0) {
#pragma unroll
            for (int j = 0; j < PH; j++) R[j] = gbuf[slot][cidx][j];
        }
    };

    auto STEP = [&](float4 g, int s, int jm) {
        int t = s - l;
        bool active = (t >= 0) && (t < TT);

        // pre-fma on h (available now) runs PARALLEL to the dpp:
        f2 h2  = {h, h};
        f2 g01 = {g.x, g.y}, g23 = {g.z, g.w};
        f2 pre01 = h2 * wh01 + g01;               // v_pk_fma_f32 candidates
        f2 pre23 = h2 * wh23 + g23;
        float hin = dpp_shr1(h);                  // h_{l-1}(t)
        f2 hin2 = {hin, hin};
        f2 u01 = hin2 * wi01 + pre01;
        f2 u23 = hin2 * wi23 + pre23;

        float E0 = fexp2(u01.x), E1 = fexp2(u01.y);
        float E2 = fexp2(u23.x), E3 = fexp2(u23.y);
        float A0 = 1.f + E0, A1 = 1.f + E1, A2 = 1.f + E2, A3 = 1.f + E3;
        float M1 = A0 * A2;
        float M2 = M1 * A1;
        float R  = frcp(M2);                      // one rcp for c-update
        float SA = (1.f - E2) * A1;
        float N  = fmaf(cs, M1, SA);
        float cn = N * R;                         // c_new
        float mc = fmed3(cn, -3.2f, 3.2f);        // Pade validity window
        float x2 = mc * mc;
        f2 x22 = {x2, x2};
        f2 c1 = {1.0f, 15.f}, c2v = {105.f, 420.f}, c3 = {945.f, 945.f};
        f2 npd = x22 * (x22 * c1 + c2v) + c3;     // {pn, pd} packed
        float RQ = frcp(npd.y * A3);              // tanh-den + o-gate fused
        float hn = (mc * npd.x) * RQ;             // h_new = o * tanh(c_new)

        if (active) { cs = cn; h = hn; }

        if (jm == 1) o0 = hn;
        else if (jm == 2) o1 = hn;
        else if (jm == 3) o2 = hn;
        else o3 = hn;                              // jm == 0
        if (jm == 0 && s >= 12 && s <= 520 && isl9) {
            float4 v;
            v.x = 60.f * frcp(1.f + fexp2(-L2E * o0));   // sigma inline again
            v.y = 60.f * frcp(1.f + fexp2(-L2E * o1));
            v.z = 60.f * frcp(1.f + fexp2(-L2E * o2));
            v.w = 60.f * frcp(1.f + fexp2(-L2E * o3));
            *(float4*)(outp + (s - 12)) = v;
        }
    };

    float4 RA[PH], RB[PH];
    float4 bbv = make_float4(bb0, bb1, bb2, bb3);
#pragma unroll
    for (int i = 0; i < PH; i++) { RA[i] = bbv; RB[i] = bbv; }

    // prologue: VA<-ph0, VB<-ph1; produce ph0; regs<-ph0; VA<-ph2
    LOADV(VA0, VA1, VA2, VA3, 0);
    LOADV(VB0, VB1, VB2, VB3, 1);
    PROD1(VA0, 0, 0); PROD1(VA1, 1, 0); PROD1(VA2, 2, 0); PROD1(VA3, 3, 0);
    READR(RA, 0);
    LOADV(VA0, VA1, VA2, VA3, 2);

    // steady state: at top RA=regs(ph p), VB=x(ph p+1), VA=x(ph p+2)
    for (int p = 0; p < PHASES; p += 2) {
        PROD1(VB0, 0, 1); PROD1(VB1, 1, 1); PROD1(VB2, 2, 1); PROD1(VB3, 3, 1);
#pragma unroll
        for (int j = 0; j < PH; j++) STEP(RA[j], p * PH + j, j & 3);
        READR(RB, 1);                                  // regs <- ph p+1
        LOADV(VB0, VB1, VB2, VB3, p + 3);

        PROD1(VA0, 0, 0); PROD1(VA1, 1, 0); PROD1(VA2, 2, 0); PROD1(VA3, 3, 0);
#pragma unroll
        for (int j = 0; j < PH; j++) STEP(RB[j], (p + 1) * PH + j, j & 3);
        READR(RA, 0);                                  // regs <- ph p+2
        LOADV(VA0, VA1, VA2, VA3, p + 4);
    }
}

extern "C" void kernel_launch(void* const* d_in, const int* in_sizes, int n_in,
                              void* d_out, int out_size, void* d_ws, size_t ws_size,
                              hipStream_t stream)
{
    const float* x    = (const float*)d_in[0];
    const float* Wih0 = (const float*)d_in[1];
    const float* Whh0 = (const float*)d_in[2];
    const float* b0   = (const float*)d_in[3];
    const float* Wihr = (const float*)d_in[4];
    const float* Whhr = (const float*)d_in[5];
    const float* br   = (const float*)d_in[6];
    float* out = (float*)d_out;

    k_fused<<<BB / CPB, 64, 0, stream>>>(x, Wih0, Whh0, b0, Wihr, Whhr, br, out);
}

// Round 18
// 84.374 us; speedup vs baseline: 1.4610x; 1.0217x over previous
//
#include <hip/hip_runtime.h>

#define BB 4096   // batch
#define TT 512    // time steps
#define DD 32     // input dim
#define NL 10     // layers
#define PH 8      // steps per phase
#define PHASES 66 // 528 steps
#define CPB 4     // chains per block (1024 blocks, 1 wave/SIMD)

static constexpr float L2E = 1.4426950408889634f;   // log2(e)
static constexpr float GCL = 26.0f;                 // producer g-clamp (scaled)

typedef float f4 __attribute__((ext_vector_type(4)));
typedef float f2 __attribute__((ext_vector_type(2)));

__device__ __forceinline__ float fexp2(float x) { return __builtin_amdgcn_exp2f(x); }
__device__ __forceinline__ float frcp(float x)  { return __builtin_amdgcn_rcpf(x); }
__device__ __forceinline__ float fmed3(float x, float a, float b) {
    return __builtin_amdgcn_fmed3f(x, a, b);
}

// row_shr:1 within each 16-lane row; row-lane 0 gets 0 (bound_ctrl).
__device__ __forceinline__ float dpp_shr1(float x) {
    int r = __builtin_amdgcn_update_dpp(0, __float_as_int(x), 0x111, 0xF, 0xF, true);
    return __int_as_float(r);
}

template<int CTRL>
__device__ __forceinline__ float dpp_add(float x) {
    return x + __int_as_float(__builtin_amdgcn_update_dpp(
        0, __float_as_int(x), CTRL, 0xF, 0xF, true));
}
#define DPP_XOR1 0xB1   // quad_perm [1,0,3,2]
#define DPP_XOR2 0x4E   // quad_perm [2,3,0,1]
#define DPP_ROR4 0x124  // row_ror:4 cross-quad gather (verified R10)

// ---------------------------------------------------------------------------
// R18 = R17 with the nt-store type fixed (ext-vector f4, not HIP float4).
// Packed producer (8 v_pk_fma_f32 per PROD1 via per-element transposed
// weights) + non-temporal out stores. Consumer STEP identical to R16.
// ---------------------------------------------------------------------------
__global__ __launch_bounds__(64) void k_fused(
    const float* __restrict__ x, const float* __restrict__ Wih0,
    const float* __restrict__ Whh0, const float* __restrict__ b0,
    const float* __restrict__ Wihr, const float* __restrict__ Whhr,
    const float* __restrict__ br, float* __restrict__ out)
{
    __shared__ float4 gbuf[2][CPB][PH + 1];   // [slot][chain][step], +1 pad

    const int lane = threadIdx.x & 63;
    const int blk  = blockIdx.x;

    // ---- producer-role constants: per-element transposed weight pairs ----
    const int pg = lane >> 3;               // step-in-phase this lane helps produce
    const int pc = lane & 7;                // float4 chunk of the 32-wide x row
    f2 wt01[4], wt23[4];
#pragma unroll
    for (int e = 0; e < 4; e++) {
        int col = pc * 4 + e;
        wt01[e] = f2{Wih0[0 * DD + col], Wih0[1 * DD + col]};
        wt23[e] = f2{Wih0[2 * DD + col], Wih0[3 * DD + col]};
    }
    const float pb0 = b0[0], pb1 = b0[1], pb2 = b0[2], pb3 = b0[3];

    // ---- consumer-role constants ----
    const int cidx = lane >> 4;             // row = chain-in-block
    const int l = lane & 15;                // 0..9 live layers
    const int chain = blk * CPB + cidx;
    const float sk0 = -L2E, sk1 = -L2E, sk2 = -2.f * L2E, sk3 = -L2E;
    const bool isl0 = (l == 0), isl9 = (l == NL - 1);
    const int li = (l >= 1 && l <= 9) ? (l - 1) : 0;

    float wi0 = 0, wi1 = 0, wi2 = 0, wi3 = 0;
    float wh0, wh1, wh2, wh3;
    float bb0 = 0, bb1 = 0, bb2 = 0, bb3 = 0;
    if (isl0) {
        wh0 = sk0 * Whh0[0]; wh1 = sk1 * Whh0[1];
        wh2 = sk2 * Whh0[2]; wh3 = sk3 * Whh0[3];
    } else {
        const float* pi = Wihr + li * 4;
        const float* ph = Whhr + li * 4;
        const float* pb = br   + li * 4;
        wi0 = sk0 * pi[0]; wi1 = sk1 * pi[1]; wi2 = sk2 * pi[2]; wi3 = sk3 * pi[3];
        wh0 = sk0 * ph[0]; wh1 = sk1 * ph[1]; wh2 = sk2 * ph[2]; wh3 = sk3 * ph[3];
        bb0 = sk0 * pb[0]; bb1 = sk1 * pb[1]; bb2 = sk2 * pb[2]; bb3 = sk3 * pb[3];
    }

    const f2 wi01 = {wi0, wi1}, wi23 = {wi2, wi3};
    const f2 wh01 = {wh0, wh1}, wh23 = {wh2, wh3};

    float* outp = out + (size_t)chain * TT;
    float h = 0.f, cs = 0.f;                // c in natural units
    float o0 = 0.f, o1 = 0.f, o2 = 0.f, o3 = 0.f;

    const float* xb = x + (size_t)blk * CPB * TT * DD;

    f4 VA0, VA1, VA2, VA3, VB0, VB1, VB2, VB3;

    auto LOADV = [&](f4& v0, f4& v1, f4& v2, f4& v3, int p) {
        int t = p * PH + pg; t = t < TT ? t : TT - 1;   // tail clamps (discarded)
        const float* base = xb + (size_t)t * DD + pc * 4;
        v0 = __builtin_nontemporal_load((const f4*)(base + 0 * TT * DD));
        v1 = __builtin_nontemporal_load((const f4*)(base + 1 * TT * DD));
        v2 = __builtin_nontemporal_load((const f4*)(base + 2 * TT * DD));
        v3 = __builtin_nontemporal_load((const f4*)(base + 3 * TT * DD));
    };

    auto PROD1 = [&](const f4 v, int ci, int slot) {    // ci, slot literal at call site
        // packed dual-gate accumulation: 8 v_pk_fma_f32
        f2 a01 = f2{v.x, v.x} * wt01[0];
        f2 a23 = f2{v.x, v.x} * wt23[0];
        a01 = f2{v.y, v.y} * wt01[1] + a01;
        a23 = f2{v.y, v.y} * wt23[1] + a23;
        a01 = f2{v.z, v.z} * wt01[2] + a01;
        a23 = f2{v.z, v.z} * wt23[2] + a23;
        a01 = f2{v.w, v.w} * wt01[3] + a01;
        a23 = f2{v.w, v.w} * wt23[3] + a23;
        float p0 = a01.x, p1 = a01.y, p2 = a23.x, p3 = a23.y;
        p0 = dpp_add<DPP_XOR1>(p0); p1 = dpp_add<DPP_XOR1>(p1);
        p2 = dpp_add<DPP_XOR1>(p2); p3 = dpp_add<DPP_XOR1>(p3);
        p0 = dpp_add<DPP_XOR2>(p0); p1 = dpp_add<DPP_XOR2>(p1);
        p2 = dpp_add<DPP_XOR2>(p2); p3 = dpp_add<DPP_XOR2>(p3);
        p0 = dpp_add<DPP_ROR4>(p0); p1 = dpp_add<DPP_ROR4>(p1);
        p2 = dpp_add<DPP_ROR4>(p2); p3 = dpp_add<DPP_ROR4>(p3);
        if (pc == 0) {
            float4 o;
            o.x = fmed3(-L2E * (p0 + pb0), -GCL, GCL);       // overflow guard
            o.y = fmed3(-L2E * (p1 + pb1), -GCL, GCL);
            o.z = fmed3(-2.f * L2E * (p2 + pb2), -GCL, GCL);
            o.w = fmed3(-L2E * (p3 + pb3), -GCL, GCL);
            gbuf[slot][ci][pg] = o;
        }
    };

    auto READR = [&](float4* R, int slot) {
        if (isl0) {
#pragma unroll
            for (int j = 0; j < PH; j++) R[j] = gbuf[slot][cidx][j];
        }
    };

    auto STEP = [&](float4 g, int s, int jm) {
        int t = s - l;
        bool active = (t >= 0) && (t < TT);

        // pre-fma on h (available now) runs PARALLEL to the dpp:
        f2 h2  = {h, h};
        f2 g01 = {g.x, g.y}, g23 = {g.z, g.w};
        f2 pre01 = h2 * wh01 + g01;               // v_pk_fma_f32
        f2 pre23 = h2 * wh23 + g23;
        float hin = dpp_shr1(h);                  // h_{l-1}(t)
        f2 hin2 = {hin, hin};
        f2 u01 = hin2 * wi01 + pre01;
        f2 u23 = hin2 * wi23 + pre23;

        float E0 = fexp2(u01.x), E1 = fexp2(u01.y);
        float E2 = fexp2(u23.x), E3 = fexp2(u23.y);
        float A0 = 1.f + E0, A1 = 1.f + E1, A2 = 1.f + E2, A3 = 1.f + E3;
        float M1 = A0 * A2;
        float M2 = M1 * A1;
        float R  = frcp(M2);                      // one rcp for c-update
        float SA = (1.f - E2) * A1;
        float N  = fmaf(cs, M1, SA);
        float cn = N * R;                         // c_new
        float mc = fmed3(cn, -3.2f, 3.2f);        // Pade validity window
        float x2 = mc * mc;
        f2 x22 = {x2, x2};
        f2 c1 = {1.0f, 15.f}, c2v = {105.f, 420.f}, c3 = {945.f, 945.f};
        f2 npd = x22 * (x22 * c1 + c2v) + c3;     // {pn, pd} packed
        float RQ = frcp(npd.y * A3);              // tanh-den + o-gate fused
        float hn = (mc * npd.x) * RQ;             // h_new = o * tanh(c_new)

        if (active) { cs = cn; h = hn; }

        if (jm == 1) o0 = hn;
        else if (jm == 2) o1 = hn;
        else if (jm == 3) o2 = hn;
        else o3 = hn;                              // jm == 0
        if (jm == 0 && s >= 12 && s <= 520 && isl9) {
            f4 v;
            v.x = 60.f * frcp(1.f + fexp2(-L2E * o0));
            v.y = 60.f * frcp(1.f + fexp2(-L2E * o1));
            v.z = 60.f * frcp(1.f + fexp2(-L2E * o2));
            v.w = 60.f * frcp(1.f + fexp2(-L2E * o3));
            __builtin_nontemporal_store(v, (f4*)(outp + (s - 12)));
        }
    };

    float4 RA[PH], RB[PH];
    float4 bbv = make_float4(bb0, bb1, bb2, bb3);
#pragma unroll
    for (int i = 0; i < PH; i++) { RA[i] = bbv; RB[i] = bbv; }

    // prologue: VA<-ph0, VB<-ph1; produce ph0; regs<-ph0; VA<-ph2
    LOADV(VA0, VA1, VA2, VA3, 0);
    LOADV(VB0, VB1, VB2, VB3, 1);
    PROD1(VA0, 0, 0); PROD1(VA1, 1, 0); PROD1(VA2, 2, 0); PROD1(VA3, 3, 0);
    READR(RA, 0);
    LOADV(VA0, VA1, VA2, VA3, 2);

    // steady state: at top RA=regs(ph p), VB=x(ph p+1), VA=x(ph p+2)
    for (int p = 0; p < PHASES; p += 2) {
        PROD1(VB0, 0, 1); PROD1(VB1, 1, 1); PROD1(VB2, 2, 1); PROD1(VB3, 3, 1);
#pragma unroll
        for (int j = 0; j < PH; j++) STEP(RA[j], p * PH + j, j & 3);
        READR(RB, 1);                                  // regs <- ph p+1
        LOADV(VB0, VB1, VB2, VB3, p + 3);

        PROD1(VA0, 0, 0); PROD1(VA1, 1, 0); PROD1(VA2, 2, 0); PROD1(VA3, 3, 0);
#pragma unroll
        for (int j = 0; j < PH; j++) STEP(RB[j], (p + 1) * PH + j, j & 3);
        READR(RA, 0);                                  // regs <- ph p+2
        LOADV(VA0, VA1, VA2, VA3, p + 4);
    }
}

extern "C" void kernel_launch(void* const* d_in, const int* in_sizes, int n_in,
                              void* d_out, int out_size, void* d_ws, size_t ws_size,
                              hipStream_t stream)
{
    const float* x    = (const float*)d_in[0];
    const float* Wih0 = (const float*)d_in[1];
    const float* Whh0 = (const float*)d_in[2];
    const float* b0   = (const float*)d_in[3];
    const float* Wihr = (const float*)d_in[4];
    const float* Whhr = (const float*)d_in[5];
    const float* br   = (const float*)d_in[6];
    float* out = (float*)d_out;

    k_fused<<<BB / CPB, 64, 0, stream>>>(x, Wih0, Whh0, b0, Wihr, Whhr, br, out);
}